// Round 6
// baseline (935.131 us; speedup 1.0000x reference)
//
#include <hip/hip_runtime.h>

// ---------------------------------------------------------------------------
// Cylindrical flow, R6 = R5 (barrier-free wave-fused, K-permuted, split-fp16)
// with the register-spill fix.
//   R5 pathology: WRITE_SIZE 790 MB (spill scratch) — compiler capped VGPRs
//   at 128 under __launch_bounds__(256,2) while ~230 live regs are needed
//   (acc2 96 + x frags 64 + a1 32 + transients). Fix: __launch_bounds__(256,1)
//   -> cap 512; expected alloc ~240 -> runtime occupancy still 2 waves/SIMD,
//   zero spill. Structure proven correct (absmax 0.03125 = R4).
// ---------------------------------------------------------------------------

typedef _Float16 f16x8 __attribute__((ext_vector_type(8)));
typedef float    f32x4 __attribute__((ext_vector_type(4)));

#define TWO_PI_F  6.28318530717958647692f
#define MIN_SZ    1e-3f
#define MIN_D_F   1e-3f
#define DERIV_OFF 0.54132485461291810f   /* ln(e-1) */

__device__ __forceinline__ float softplus_f(float x) {
    return fmaxf(x, 0.f) + log1pf(__expf(-fabsf(x)));
}

// ---------------------------------------------------------------------------
// Prep: pack W1 (std A-fragment order) and W2 (K-permuted A-fragment order),
// each as hi/lo fp16 split.
// W1 frag (ht,kx): lane l, j: A[h = ht*16+(l&15)][k = kx*32+(l>>4)*8+j]
// W2 frag (pt,kb): lane l, j: A[p = pt*16+(l&15)][h = (2kb+(j>>2))*16+(l>>4)*4+(j&3)]
// ---------------------------------------------------------------------------
__global__ void flow_prep(const float* __restrict__ W1, const float* __restrict__ W2,
                          _Float16* __restrict__ w1h, _Float16* __restrict__ w1l,
                          _Float16* __restrict__ w2h, _Float16* __restrict__ w2l) {
    int i = blockIdx.x * 256 + threadIdx.x;
    if (i < 16384) {                       // w1: [16 ht][2 kx][64 l][8 j]
        int j = i & 7, l = (i >> 3) & 63, kx = (i >> 9) & 1, ht = i >> 10;
        int h = ht * 16 + (l & 15);
        int k = kx * 32 + (l >> 4) * 8 + j;
        float v = W1[k * 256 + h];         // W1 (64,256) row-major
        _Float16 hv = (_Float16)v;
        w1h[i] = hv;
        w1l[i] = (_Float16)(v - (float)hv);
    }
    int i2 = i - 16384;
    if (i2 >= 0 && i2 < 24576) {           // w2: [6 pt][8 kb][64 l][8 j], K-permuted
        int j = i2 & 7, l = (i2 >> 3) & 63, kb = (i2 >> 9) & 7, pt = i2 >> 12;
        int p = pt * 16 + (l & 15);
        int h = (2 * kb + (j >> 2)) * 16 + ((l >> 4) << 2) + (j & 3);
        float v = W2[h * 96 + p];          // W2 (256,96) row-major
        _Float16 hv = (_Float16)v;
        w2h[i2] = hv;
        w2l[i2] = (_Float16)(v - (float)hv);
    }
}

__global__ __launch_bounds__(256, 1) void flow_main(
    const float* __restrict__ theta, const float* __restrict__ xc,
    const float* __restrict__ b1g, const float* __restrict__ b2g,
    const float* __restrict__ etag,
    const _Float16* __restrict__ w1h, const _Float16* __restrict__ w1l,
    const _Float16* __restrict__ w2h, const _Float16* __restrict__ w2l,
    float* __restrict__ out, int Btot)
{
    __shared__ __align__(16) float sP[4 * 32 * 97];   // per-wave 32x97 scratch
    __shared__ float sB1[256];
    __shared__ float sB2[96];

    const int t   = threadIdx.x;
    const int wid = t >> 6;
    const int l   = t & 63;
    const int q   = l >> 4;
    const int lc  = l & 15;
    const long R0w = ((long)blockIdx.x * 4 + wid) * 64;

    if (t < 256) sB1[t] = b1g[t];
    if (t < 96)  sB2[t] = b2g[t];
    __syncthreads();                       // only barrier in the kernel
    const float ev = etag[0];

    const f16x8* w1vh = (const f16x8*)w1h;
    const f16x8* w1vl = (const f16x8*)w1l;
    const f16x8* w2vh = (const f16x8*)w2h;
    const f16x8* w2vl = (const f16x8*)w2l;

    // ---- load x fragments for this wave's 64 rows (persistent) -------------
    f16x8 xh[4][2], xl[4][2];
    #pragma unroll
    for (int mt = 0; mt < 4; ++mt)
        #pragma unroll
        for (int kx = 0; kx < 2; ++kx) {
            const float* xp = xc + (R0w + mt * 16 + lc) * 64 + kx * 32 + q * 8;
            float4 v0 = *(const float4*)xp;
            float4 v1 = *(const float4*)(xp + 4);
            f16x8 hi, lo;
            hi[0] = (_Float16)v0.x; lo[0] = (_Float16)(v0.x - (float)hi[0]);
            hi[1] = (_Float16)v0.y; lo[1] = (_Float16)(v0.y - (float)hi[1]);
            hi[2] = (_Float16)v0.z; lo[2] = (_Float16)(v0.z - (float)hi[2]);
            hi[3] = (_Float16)v0.w; lo[3] = (_Float16)(v0.w - (float)hi[3]);
            hi[4] = (_Float16)v1.x; lo[4] = (_Float16)(v1.x - (float)hi[4]);
            hi[5] = (_Float16)v1.y; lo[5] = (_Float16)(v1.y - (float)hi[5]);
            hi[6] = (_Float16)v1.z; lo[6] = (_Float16)(v1.z - (float)hi[6]);
            hi[7] = (_Float16)v1.w; lo[7] = (_Float16)(v1.w - (float)hi[7]);
            xh[mt][kx] = hi;
            xl[mt][kx] = lo;
        }

    // ---- fused K-loop: per kb, GEMM1 (2 h-tiles) -> relu/split -> GEMM2 ----
    f32x4 acc2[6][4] = {};
    #pragma unroll 2
    for (int kb = 0; kb < 8; ++kb) {
        f32x4 a1[2][4] = {};
        #pragma unroll
        for (int i = 0; i < 2; ++i) {
            const int ht = 2 * kb + i;
            #pragma unroll
            for (int kx = 0; kx < 2; ++kx) {
                f16x8 wh = w1vh[(ht * 2 + kx) * 64 + l];   // 1 KB coalesced
                f16x8 wl = w1vl[(ht * 2 + kx) * 64 + l];
                #pragma unroll
                for (int mt = 0; mt < 4; ++mt) {
                    a1[i][mt] = __builtin_amdgcn_mfma_f32_16x16x32_f16(wl, xh[mt][kx], a1[i][mt], 0, 0, 0);
                    a1[i][mt] = __builtin_amdgcn_mfma_f32_16x16x32_f16(wh, xl[mt][kx], a1[i][mt], 0, 0, 0);
                    a1[i][mt] = __builtin_amdgcn_mfma_f32_16x16x32_f16(wh, xh[mt][kx], a1[i][mt], 0, 0, 0);
                }
            }
        }
        // epilogue: bias+relu+split; GEMM1 C-layout IS GEMM2 B-frag (K-perm)
        f16x8 bh[4], bl[4];
        float4 bb0 = *(const float4*)(sB1 + (2 * kb + 0) * 16 + q * 4);
        float4 bb1 = *(const float4*)(sB1 + (2 * kb + 1) * 16 + q * 4);
        #pragma unroll
        for (int mt = 0; mt < 4; ++mt) {
            f16x8 hi, lo;
            float v;
            v = fmaxf(a1[0][mt][0] + bb0.x, 0.f); hi[0] = (_Float16)v; lo[0] = (_Float16)(v - (float)hi[0]);
            v = fmaxf(a1[0][mt][1] + bb0.y, 0.f); hi[1] = (_Float16)v; lo[1] = (_Float16)(v - (float)hi[1]);
            v = fmaxf(a1[0][mt][2] + bb0.z, 0.f); hi[2] = (_Float16)v; lo[2] = (_Float16)(v - (float)hi[2]);
            v = fmaxf(a1[0][mt][3] + bb0.w, 0.f); hi[3] = (_Float16)v; lo[3] = (_Float16)(v - (float)hi[3]);
            v = fmaxf(a1[1][mt][0] + bb1.x, 0.f); hi[4] = (_Float16)v; lo[4] = (_Float16)(v - (float)hi[4]);
            v = fmaxf(a1[1][mt][1] + bb1.y, 0.f); hi[5] = (_Float16)v; lo[5] = (_Float16)(v - (float)hi[5]);
            v = fmaxf(a1[1][mt][2] + bb1.z, 0.f); hi[6] = (_Float16)v; lo[6] = (_Float16)(v - (float)hi[6]);
            v = fmaxf(a1[1][mt][3] + bb1.w, 0.f); hi[7] = (_Float16)v; lo[7] = (_Float16)(v - (float)hi[7]);
            bh[mt] = hi;
            bl[mt] = lo;
        }
        #pragma unroll
        for (int pt = 0; pt < 6; ++pt) {
            f16x8 wh = w2vh[(pt * 8 + kb) * 64 + l];       // 1 KB coalesced
            f16x8 wl = w2vl[(pt * 8 + kb) * 64 + l];
            #pragma unroll
            for (int mt = 0; mt < 4; ++mt) {
                acc2[pt][mt] = __builtin_amdgcn_mfma_f32_16x16x32_f16(wl, bh[mt], acc2[pt][mt], 0, 0, 0);
                acc2[pt][mt] = __builtin_amdgcn_mfma_f32_16x16x32_f16(wh, bl[mt], acc2[pt][mt], 0, 0, 0);
                acc2[pt][mt] = __builtin_amdgcn_mfma_f32_16x16x32_f16(wh, bh[mt], acc2[pt][mt], 0, 0, 0);
            }
        }
    }

    // ---- spline: 2 rounds of 32 rows, wave-private LDS, no barriers --------
    float* sPw = sP + wid * (32 * 97);
    #pragma unroll 1
    for (int rd = 0; rd < 2; ++rd) {
        // write P[r][p] = (acc2 + b2)*eta ; r = mtl*16+lc, p = pt*16+q*4
        #pragma unroll
        for (int pt = 0; pt < 6; ++pt) {
            float4 bb = *(const float4*)(sB2 + pt * 16 + q * 4);
            #pragma unroll
            for (int mtl = 0; mtl < 2; ++mtl) {
                f32x4 v = acc2[pt][rd * 2 + mtl];
                float* dst = sPw + (mtl * 16 + lc) * 97 + pt * 16 + q * 4;
                dst[0] = (v[0] + bb.x) * ev;
                dst[1] = (v[1] + bb.y) * ev;
                dst[2] = (v[2] + bb.z) * ev;
                dst[3] = (v[3] + bb.w) * ev;
            }
        }
        // knots: 64 lanes = 32 rows x {widths, heights}; in-place, col j ends
        // holding knot_{j+1} (knot_0 = 0 implicit)
        {
            int row = l & 31;
            float* rowp = sPw + row * 97 + ((l >> 5) << 5);
            float mx = rowp[0];
            #pragma unroll
            for (int j = 1; j < 32; ++j) mx = fmaxf(mx, rowp[j]);
            float S = 0.f;
            #pragma unroll
            for (int j = 0; j < 32; ++j) {
                float e = __expf(rowp[j] - mx);
                rowp[j] = e;
                S += e;
            }
            float scale = (1.0f - 32.0f * MIN_SZ) / S;
            float c = 0.f;
            #pragma unroll
            for (int j = 0; j < 32; ++j) {
                c += rowp[j];
                rowp[j] = TWO_PI_F * fmaf(scale, c, MIN_SZ * (float)(j + 1));
            }
            rowp[31] = TWO_PI_F;
        }
        // eval + store: lanes 0..31
        if (l < 32) {
            const float* row = sPw + l * 97;
            long gr = R0w + rd * 32 + l;
            float th_in = theta[gr];
            int bin = 0;
            #pragma unroll
            for (int j = 0; j < 32; ++j) bin += (th_in >= row[j]) ? 1 : 0;
            bin = min(bin, 31);

            float cwk1 = row[bin];
            float cwk0 = (bin == 0) ? 0.f : row[bin - 1];
            float chk1 = row[32 + bin];
            float chk0 = (bin == 0) ? 0.f : row[32 + bin - 1];
            float in_w = cwk1 - cwk0;
            float in_h = chk1 - chk0;
            float d_k  = MIN_D_F + softplus_f(row[64 + bin] + DERIV_OFF);
            float d_k1 = MIN_D_F + softplus_f(row[64 + ((bin + 1) & 31)] + DERIV_OFF);

            float s   = in_h / in_w;
            float tt  = (th_in - cwk0) / in_w;
            float tom = tt * (1.f - tt);
            float denom = s + (d_k1 + d_k - 2.f * s) * tom;
            float numer = in_h * (s * tt * tt + d_k * tom);
            float outv  = chk0 + numer / denom;
            float omt   = 1.f - tt;
            float dnum  = s * s * (d_k1 * tt * tt + 2.f * s * tom + d_k * omt * omt);
            float lad   = __logf(dnum) - 2.f * __logf(denom);

            out[gr]               = outv;
            out[(long)Btot + gr]  = lad;
        }
    }
}

extern "C" void kernel_launch(void* const* d_in, const int* in_sizes, int n_in,
                              void* d_out, int out_size, void* d_ws, size_t ws_size,
                              hipStream_t stream) {
    const float* theta = (const float*)d_in[0];
    const float* xcond = (const float*)d_in[1];
    const float* W1    = (const float*)d_in[2];
    const float* b1    = (const float*)d_in[3];
    const float* W2    = (const float*)d_in[4];
    const float* b2    = (const float*)d_in[5];
    const float* eta   = (const float*)d_in[6];
    int Btot = in_sizes[0];                    // 1048576 (d = 1)

    _Float16* w1h = (_Float16*)d_ws;           // 16384 f16
    _Float16* w1l = w1h + 16384;
    _Float16* w2h = w1l + 16384;               // 24576 f16
    _Float16* w2l = w2h + 24576;               // total 160 KiB of ws

    flow_prep<<<160, 256, 0, stream>>>(W1, W2, w1h, w1l, w2h, w2l);
    // 64 rows per wave, 4 waves per block -> 256 rows/block
    flow_main<<<Btot / 256, 256, 0, stream>>>(theta, xcond, b1, b2, eta,
                                              w1h, w1l, w2h, w2l,
                                              (float*)d_out, Btot);
}

// Round 7
// 621.703 us; speedup vs baseline: 1.5041x; 1.5041x over previous
//
#include <hip/hip_runtime.h>

// ---------------------------------------------------------------------------
// Cylindrical flow, R7 = R5/R6 wave-fused structure with the REAL spill fix.
//   R5/R6's 700-790 MB WRITE_SIZE was a scratch alloca: the spline loop
//   (#pragma unroll 1) indexed acc2[pt][rd*2+mtl] with dynamic rd -> LLVM
//   lowered the accumulator array to scratch (96 regs x 64 lanes x 16K waves
//   ~ 400+ MB traffic). Budget was never the issue ((256,1) still chose 140).
//   Fix: fully unroll rd -> constant indices -> registers. launch_bounds
//   (256,2): 256-reg budget fits ~240 live set, 2 blocks/CU.
// ---------------------------------------------------------------------------

typedef _Float16 f16x8 __attribute__((ext_vector_type(8)));
typedef float    f32x4 __attribute__((ext_vector_type(4)));

#define TWO_PI_F  6.28318530717958647692f
#define MIN_SZ    1e-3f
#define MIN_D_F   1e-3f
#define DERIV_OFF 0.54132485461291810f   /* ln(e-1) */

__device__ __forceinline__ float softplus_f(float x) {
    return fmaxf(x, 0.f) + log1pf(__expf(-fabsf(x)));
}

// ---------------------------------------------------------------------------
// Prep: pack W1 (std A-fragment order) and W2 (K-permuted A-fragment order),
// each as hi/lo fp16 split.
// W1 frag (ht,kx): lane l, j: A[h = ht*16+(l&15)][k = kx*32+(l>>4)*8+j]
// W2 frag (pt,kb): lane l, j: A[p = pt*16+(l&15)][h = (2kb+(j>>2))*16+(l>>4)*4+(j&3)]
// ---------------------------------------------------------------------------
__global__ void flow_prep(const float* __restrict__ W1, const float* __restrict__ W2,
                          _Float16* __restrict__ w1h, _Float16* __restrict__ w1l,
                          _Float16* __restrict__ w2h, _Float16* __restrict__ w2l) {
    int i = blockIdx.x * 256 + threadIdx.x;
    if (i < 16384) {                       // w1: [16 ht][2 kx][64 l][8 j]
        int j = i & 7, l = (i >> 3) & 63, kx = (i >> 9) & 1, ht = i >> 10;
        int h = ht * 16 + (l & 15);
        int k = kx * 32 + (l >> 4) * 8 + j;
        float v = W1[k * 256 + h];         // W1 (64,256) row-major
        _Float16 hv = (_Float16)v;
        w1h[i] = hv;
        w1l[i] = (_Float16)(v - (float)hv);
    }
    int i2 = i - 16384;
    if (i2 >= 0 && i2 < 24576) {           // w2: [6 pt][8 kb][64 l][8 j], K-permuted
        int j = i2 & 7, l = (i2 >> 3) & 63, kb = (i2 >> 9) & 7, pt = i2 >> 12;
        int p = pt * 16 + (l & 15);
        int h = (2 * kb + (j >> 2)) * 16 + ((l >> 4) << 2) + (j & 3);
        float v = W2[h * 96 + p];          // W2 (256,96) row-major
        _Float16 hv = (_Float16)v;
        w2h[i2] = hv;
        w2l[i2] = (_Float16)(v - (float)hv);
    }
}

__global__ __launch_bounds__(256, 2) void flow_main(
    const float* __restrict__ theta, const float* __restrict__ xc,
    const float* __restrict__ b1g, const float* __restrict__ b2g,
    const float* __restrict__ etag,
    const _Float16* __restrict__ w1h, const _Float16* __restrict__ w1l,
    const _Float16* __restrict__ w2h, const _Float16* __restrict__ w2l,
    float* __restrict__ out, int Btot)
{
    __shared__ __align__(16) float sP[4 * 32 * 97];   // per-wave 32x97 scratch
    __shared__ float sB1[256];
    __shared__ float sB2[96];

    const int t   = threadIdx.x;
    const int wid = t >> 6;
    const int l   = t & 63;
    const int q   = l >> 4;
    const int lc  = l & 15;
    const long R0w = ((long)blockIdx.x * 4 + wid) * 64;

    if (t < 256) sB1[t] = b1g[t];
    if (t < 96)  sB2[t] = b2g[t];
    __syncthreads();                       // only barrier in the kernel
    const float ev = etag[0];

    const f16x8* w1vh = (const f16x8*)w1h;
    const f16x8* w1vl = (const f16x8*)w1l;
    const f16x8* w2vh = (const f16x8*)w2h;
    const f16x8* w2vl = (const f16x8*)w2l;

    // ---- load x fragments for this wave's 64 rows (persistent) -------------
    f16x8 xh[4][2], xl[4][2];
    #pragma unroll
    for (int mt = 0; mt < 4; ++mt)
        #pragma unroll
        for (int kx = 0; kx < 2; ++kx) {
            const float* xp = xc + (R0w + mt * 16 + lc) * 64 + kx * 32 + q * 8;
            float4 v0 = *(const float4*)xp;
            float4 v1 = *(const float4*)(xp + 4);
            f16x8 hi, lo;
            hi[0] = (_Float16)v0.x; lo[0] = (_Float16)(v0.x - (float)hi[0]);
            hi[1] = (_Float16)v0.y; lo[1] = (_Float16)(v0.y - (float)hi[1]);
            hi[2] = (_Float16)v0.z; lo[2] = (_Float16)(v0.z - (float)hi[2]);
            hi[3] = (_Float16)v0.w; lo[3] = (_Float16)(v0.w - (float)hi[3]);
            hi[4] = (_Float16)v1.x; lo[4] = (_Float16)(v1.x - (float)hi[4]);
            hi[5] = (_Float16)v1.y; lo[5] = (_Float16)(v1.y - (float)hi[5]);
            hi[6] = (_Float16)v1.z; lo[6] = (_Float16)(v1.z - (float)hi[6]);
            hi[7] = (_Float16)v1.w; lo[7] = (_Float16)(v1.w - (float)hi[7]);
            xh[mt][kx] = hi;
            xl[mt][kx] = lo;
        }

    // ---- fused K-loop: per kb, GEMM1 (2 h-tiles) -> relu/split -> GEMM2 ----
    f32x4 acc2[6][4] = {};
    #pragma unroll 2
    for (int kb = 0; kb < 8; ++kb) {
        f32x4 a1[2][4] = {};
        #pragma unroll
        for (int i = 0; i < 2; ++i) {
            const int ht = 2 * kb + i;
            #pragma unroll
            for (int kx = 0; kx < 2; ++kx) {
                f16x8 wh = w1vh[(ht * 2 + kx) * 64 + l];   // 1 KB coalesced
                f16x8 wl = w1vl[(ht * 2 + kx) * 64 + l];
                #pragma unroll
                for (int mt = 0; mt < 4; ++mt) {
                    a1[i][mt] = __builtin_amdgcn_mfma_f32_16x16x32_f16(wl, xh[mt][kx], a1[i][mt], 0, 0, 0);
                    a1[i][mt] = __builtin_amdgcn_mfma_f32_16x16x32_f16(wh, xl[mt][kx], a1[i][mt], 0, 0, 0);
                    a1[i][mt] = __builtin_amdgcn_mfma_f32_16x16x32_f16(wh, xh[mt][kx], a1[i][mt], 0, 0, 0);
                }
            }
        }
        // epilogue: bias+relu+split; GEMM1 C-layout IS GEMM2 B-frag (K-perm)
        f16x8 bh[4], bl[4];
        float4 bb0 = *(const float4*)(sB1 + (2 * kb + 0) * 16 + q * 4);
        float4 bb1 = *(const float4*)(sB1 + (2 * kb + 1) * 16 + q * 4);
        #pragma unroll
        for (int mt = 0; mt < 4; ++mt) {
            f16x8 hi, lo;
            float v;
            v = fmaxf(a1[0][mt][0] + bb0.x, 0.f); hi[0] = (_Float16)v; lo[0] = (_Float16)(v - (float)hi[0]);
            v = fmaxf(a1[0][mt][1] + bb0.y, 0.f); hi[1] = (_Float16)v; lo[1] = (_Float16)(v - (float)hi[1]);
            v = fmaxf(a1[0][mt][2] + bb0.z, 0.f); hi[2] = (_Float16)v; lo[2] = (_Float16)(v - (float)hi[2]);
            v = fmaxf(a1[0][mt][3] + bb0.w, 0.f); hi[3] = (_Float16)v; lo[3] = (_Float16)(v - (float)hi[3]);
            v = fmaxf(a1[1][mt][0] + bb1.x, 0.f); hi[4] = (_Float16)v; lo[4] = (_Float16)(v - (float)hi[4]);
            v = fmaxf(a1[1][mt][1] + bb1.y, 0.f); hi[5] = (_Float16)v; lo[5] = (_Float16)(v - (float)hi[5]);
            v = fmaxf(a1[1][mt][2] + bb1.z, 0.f); hi[6] = (_Float16)v; lo[6] = (_Float16)(v - (float)hi[6]);
            v = fmaxf(a1[1][mt][3] + bb1.w, 0.f); hi[7] = (_Float16)v; lo[7] = (_Float16)(v - (float)hi[7]);
            bh[mt] = hi;
            bl[mt] = lo;
        }
        #pragma unroll
        for (int pt = 0; pt < 6; ++pt) {
            f16x8 wh = w2vh[(pt * 8 + kb) * 64 + l];       // 1 KB coalesced
            f16x8 wl = w2vl[(pt * 8 + kb) * 64 + l];
            #pragma unroll
            for (int mt = 0; mt < 4; ++mt) {
                acc2[pt][mt] = __builtin_amdgcn_mfma_f32_16x16x32_f16(wl, bh[mt], acc2[pt][mt], 0, 0, 0);
                acc2[pt][mt] = __builtin_amdgcn_mfma_f32_16x16x32_f16(wh, bl[mt], acc2[pt][mt], 0, 0, 0);
                acc2[pt][mt] = __builtin_amdgcn_mfma_f32_16x16x32_f16(wh, bh[mt], acc2[pt][mt], 0, 0, 0);
            }
        }
    }

    // ---- spline: 2 rounds of 32 rows, wave-private LDS, no barriers --------
    // FULLY UNROLLED (constant rd) so acc2 indices are compile-time -> no
    // scratch alloca (R5/R6's 700 MB spill).
    float* sPw = sP + wid * (32 * 97);
    #pragma unroll
    for (int rd = 0; rd < 2; ++rd) {
        // write P[r][p] = (acc2 + b2)*eta ; r = mtl*16+lc, p = pt*16+q*4
        #pragma unroll
        for (int pt = 0; pt < 6; ++pt) {
            float4 bb = *(const float4*)(sB2 + pt * 16 + q * 4);
            #pragma unroll
            for (int mtl = 0; mtl < 2; ++mtl) {
                f32x4 v = acc2[pt][rd * 2 + mtl];
                float* dst = sPw + (mtl * 16 + lc) * 97 + pt * 16 + q * 4;
                dst[0] = (v[0] + bb.x) * ev;
                dst[1] = (v[1] + bb.y) * ev;
                dst[2] = (v[2] + bb.z) * ev;
                dst[3] = (v[3] + bb.w) * ev;
            }
        }
        // knots: 64 lanes = 32 rows x {widths, heights}; in-place, col j ends
        // holding knot_{j+1} (knot_0 = 0 implicit)
        {
            int row = l & 31;
            float* rowp = sPw + row * 97 + ((l >> 5) << 5);
            float mx = rowp[0];
            #pragma unroll
            for (int j = 1; j < 32; ++j) mx = fmaxf(mx, rowp[j]);
            float S = 0.f;
            #pragma unroll
            for (int j = 0; j < 32; ++j) {
                float e = __expf(rowp[j] - mx);
                rowp[j] = e;
                S += e;
            }
            float scale = (1.0f - 32.0f * MIN_SZ) / S;
            float c = 0.f;
            #pragma unroll
            for (int j = 0; j < 32; ++j) {
                c += rowp[j];
                rowp[j] = TWO_PI_F * fmaf(scale, c, MIN_SZ * (float)(j + 1));
            }
            rowp[31] = TWO_PI_F;
        }
        // eval + store: lanes 0..31
        if (l < 32) {
            const float* row = sPw + l * 97;
            long gr = R0w + rd * 32 + l;
            float th_in = theta[gr];
            int bin = 0;
            #pragma unroll
            for (int j = 0; j < 32; ++j) bin += (th_in >= row[j]) ? 1 : 0;
            bin = min(bin, 31);

            float cwk1 = row[bin];
            float cwk0 = (bin == 0) ? 0.f : row[bin - 1];
            float chk1 = row[32 + bin];
            float chk0 = (bin == 0) ? 0.f : row[32 + bin - 1];
            float in_w = cwk1 - cwk0;
            float in_h = chk1 - chk0;
            float d_k  = MIN_D_F + softplus_f(row[64 + bin] + DERIV_OFF);
            float d_k1 = MIN_D_F + softplus_f(row[64 + ((bin + 1) & 31)] + DERIV_OFF);

            float s   = in_h / in_w;
            float tt  = (th_in - cwk0) / in_w;
            float tom = tt * (1.f - tt);
            float denom = s + (d_k1 + d_k - 2.f * s) * tom;
            float numer = in_h * (s * tt * tt + d_k * tom);
            float outv  = chk0 + numer / denom;
            float omt   = 1.f - tt;
            float dnum  = s * s * (d_k1 * tt * tt + 2.f * s * tom + d_k * omt * omt);
            float lad   = __logf(dnum) - 2.f * __logf(denom);

            out[gr]               = outv;
            out[(long)Btot + gr]  = lad;
        }
    }
}

extern "C" void kernel_launch(void* const* d_in, const int* in_sizes, int n_in,
                              void* d_out, int out_size, void* d_ws, size_t ws_size,
                              hipStream_t stream) {
    const float* theta = (const float*)d_in[0];
    const float* xcond = (const float*)d_in[1];
    const float* W1    = (const float*)d_in[2];
    const float* b1    = (const float*)d_in[3];
    const float* W2    = (const float*)d_in[4];
    const float* b2    = (const float*)d_in[5];
    const float* eta   = (const float*)d_in[6];
    int Btot = in_sizes[0];                    // 1048576 (d = 1)

    _Float16* w1h = (_Float16*)d_ws;           // 16384 f16
    _Float16* w1l = w1h + 16384;
    _Float16* w2h = w1l + 16384;               // 24576 f16
    _Float16* w2l = w2h + 24576;               // total 160 KiB of ws

    flow_prep<<<160, 256, 0, stream>>>(W1, W2, w1h, w1l, w2h, w2l);
    // 64 rows per wave, 4 waves per block -> 256 rows/block
    flow_main<<<Btot / 256, 256, 0, stream>>>(theta, xcond, b1, b2, eta,
                                              w1h, w1l, w2h, w2l,
                                              (float*)d_out, Btot);
}